// Round 6
// baseline (437.655 us; speedup 1.0000x reference)
//
#include <hip/hip_runtime.h>
#include <hip/hip_cooperative_groups.h>
#include <stdint.h>

namespace cg = cooperative_groups;

#define NN 1536
#define EE 49152
#define EMB 32
#define HEADS 3
#define SLOPE 0.2f
#define GRID 512

__device__ __forceinline__ float lrelu(float x){ return x >= 0.f ? x : SLOPE*x; }

// ---- runtime detection of bool-mask storage (int32 / uint8 / f32) ----
__device__ int detect_mask_layout(const unsigned char* p){
  const int* pi = (const int*)p;
  bool ok = true;
  for (int k=0;k<64 && ok;k++){ int v = pi[k]; ok = (v==0 || v==1); }
  if (ok) return 0;                       // int32 0/1
  ok = true;
  for (int k=0;k<256 && ok;k++){ ok = (p[k] <= 1); }
  if (ok) return 1;                       // uint8 bool
  return 2;                               // f32 0.0/1.0
}
__device__ bool mask_at(const unsigned char* p, int layout, int i){
  if (layout==0) return ((const int*)p)[i] != 0;
  if (layout==1) return p[i] != 0;
  return ((const float*)p)[i] != 0.f;
}

// ---- LDS phase union (max ~39 KB -> 4 blocks/CU; grid 512 needs only 2) ----
struct PhaseNode {
  float sWvehT[EMB*33], sWpedT[EMB*33], sWunT[EMB*33];
  float sWt[HEADS*EMB], sWn[HEADS*EMB];
  float sF[8*EMB], sEmb[8*EMB], sLr[EMB];
  int layout;
};
struct PhasePairs {
  float sWea[EMB*2], sWet[EMB*2], sWedge[HEADS*64], sWue[EMB*33];
  float sA[8*33], sT[8*33];
};
struct PhaseRows {
  int   dst_c[256];
  float s_c[3][256], p_c[3][256];
  float u_c[256*EMB];
  float red[3][4], bcast[3];
};
union SMem { PhaseNode n; PhasePairs p; PhaseRows r; };

__global__ __launch_bounds__(256, 2) void k_fused(
    const float* __restrict__ node_f, const float* __restrict__ edge_attr,
    const float* __restrict__ edge_type,
    const float* __restrict__ W_veh, const float* __restrict__ W_ped,
    const float* __restrict__ W_ea,  const float* __restrict__ W_et,
    const float* __restrict__ W_att, const float* __restrict__ W_upd,
    const int* __restrict__ ei, const unsigned char* __restrict__ veh_mask,
    float* __restrict__ out,
    int* M, int* cnt, int* fill, float* slnb, int* offs, int* nxt,
    int* heads, int* dsts, float* se_s, float* eau_s,
    float* tar, float* nbr, float* nb)
{
  cg::grid_group grid = cg::this_grid();
  __shared__ SMem sm;
  __shared__ int ws4[4];
  const int t = threadIdx.x;
  const int b = blockIdx.x;
  const int gtid = b*256 + t;              // 0 .. GRID*256-1 (131072)

  // ---------------- P0: clear ----------------
  {
    int4* M4 = (int4*)M;
    const int n4 = NN*NN/4;
    const int4 neg1 = make_int4(-1,-1,-1,-1);
    for (int i = gtid; i < n4; i += GRID*256) M4[i] = neg1;
    if (gtid < NN){ cnt[gtid] = 0; fill[gtid] = 0; }
    if (gtid < EMB) slnb[gtid] = 0.f;
  }
  grid.sync();

  // ---------------- P1: edge claim + node embeddings ----------------
  if (gtid < EE){
    const int s = ei[gtid], d = ei[EE + gtid];
    const int old = atomicExch(&M[s*NN + d], gtid);
    nxt[gtid] = old;
    if (old == -1) atomicAdd(&cnt[s], 1);
  }
  if (b < NN/8){
    const int i0 = b*8;
    if (t == 0) sm.n.layout = detect_mask_layout(veh_mask);
    if (t < EMB) sm.n.sLr[t] = 0.f;
    for (int idx=t; idx<EMB*EMB; idx+=256){
      const int mm = idx>>5, kk = idx&31;
      sm.n.sWvehT[mm*33+kk] = W_veh[idx];
      sm.n.sWpedT[mm*33+kk] = W_ped[idx];
      sm.n.sWunT[mm*33+kk]  = W_upd[mm*64 + EMB + kk];   // Wu_n = W_upd[:,32:]
    }
    if (t < HEADS*EMB){
      const int h = t>>5, c = t&31;
      sm.n.sWt[t] = W_att[h*128 + c];        // W_tar = W_att[:, :32]
      sm.n.sWn[t] = W_att[h*128 + 96 + c];   // W_nbr = W_att[:, 96:128]
    }
    sm.n.sF[t] = node_f[(size_t)i0*EMB + t];
    __syncthreads();

    const int li = t >> 5, m = t & 31;
    const int i = i0 + li;
    const bool veh = mask_at(veh_mask, sm.n.layout, i);
    const float* WT = veh ? sm.n.sWvehT : sm.n.sWpedT;
    float a = 0.f;
    #pragma unroll
    for (int k=0;k<EMB;k++) a += sm.n.sF[li*EMB+k] * WT[m*33+k];
    sm.n.sEmb[li*EMB+m] = lrelu(a);
    __syncthreads();

    float bb = 0.f;
    #pragma unroll
    for (int k=0;k<EMB;k++) bb += sm.n.sEmb[li*EMB+k] * sm.n.sWunT[m*33+k];
    nb[(size_t)i*EMB + m] = bb;
    atomicAdd(&sm.n.sLr[m], lrelu(bb));
    if (m < 3){
      float v = 0.f;
      #pragma unroll
      for (int k=0;k<EMB;k++) v += sm.n.sEmb[li*EMB+k] * sm.n.sWt[m*EMB+k];
      tar[i*4+m] = v;
    } else if (m < 6){
      const int h = m-3;
      float v = 0.f;
      #pragma unroll
      for (int k=0;k<EMB;k++) v += sm.n.sEmb[li*EMB+k] * sm.n.sWn[h*EMB+k];
      nbr[i*4+h] = v;
    }
    __syncthreads();
    if (t < EMB) atomicAdd(&slnb[t], sm.n.sLr[t]);
  }
  grid.sync();

  // ---------------- P2: exclusive scan (block 0) ----------------
  if (b == 0){
    const int lane = t & 63, wid = t >> 6;
    const int base = t*6;
    int v[6]; int s = 0;
    for (int k=0;k<6;k++){ v[k] = cnt[base+k]; s += v[k]; }
    int x = s;
    for (int d=1; d<64; d<<=1){ int y = __shfl_up(x, d, 64); if (lane >= d) x += y; }
    if (lane==63) ws4[wid] = x;
    __syncthreads();
    if (t==0){ int a=0; for (int w=0;w<4;w++){ int tmp=ws4[w]; ws4[w]=a; a+=tmp; } }
    __syncthreads();
    int run = (x - s) + ws4[wid];
    for (int k=0;k<6;k++){ offs[base+k] = run; run += v[k]; }
    if (t==255) offs[NN] = run;
  }
  grid.sync();

  // ---------------- P3: slot assignment ----------------
  if (gtid < EE){
    const int s = ei[gtid], d = ei[EE + gtid];
    if (M[s*NN + d] == gtid){
      const int pos = offs[s] + atomicAdd(&fill[s], 1);
      heads[pos] = gtid;
      dsts[pos] = d;
    }
  }
  grid.sync();

  // ---------------- P4: per-pair embeddings -> se/eau ----------------
  {
    if (t < EMB*2){ sm.p.sWea[t]=W_ea[t]; sm.p.sWet[t]=W_et[t]; }
    if (t < HEADS*64) sm.p.sWedge[t] = W_att[(t>>6)*128 + EMB + (t&63)];
    for (int idx=t; idx<EMB*EMB; idx+=256){
      const int o = idx>>5, m = idx&31;
      sm.p.sWue[o*33+m] = W_upd[o*64 + m];
    }
    __syncthreads();
    const int Np = offs[NN];
    const int li = t >> 5, m = t & 31;
    for (int g = b; g*8 < Np; g += GRID){
      const int pos = g*8 + li;
      const bool live = (pos < Np);
      if (live){
        float am = 0.f, tm = 0.f;
        const float wa0 = sm.p.sWea[m*2], wa1 = sm.p.sWea[m*2+1];
        const float wt0 = sm.p.sWet[m*2], wt1 = sm.p.sWet[m*2+1];
        int e = heads[pos];
        while (e >= 0){                        // dup chain; length 1 for ~99.4%
          const float ea0 = edge_attr[e*2],  ea1 = edge_attr[e*2+1];
          const float et0 = edge_type[e*2],  et1 = edge_type[e*2+1];
          am += lrelu(ea0*wa0 + ea1*wa1);
          tm += lrelu(et0*wt0 + et1*wt1);
          e = nxt[e];
        }
        sm.p.sA[li*33+m] = am;
        sm.p.sT[li*33+m] = tm;
      }
      __syncthreads();
      if (live){
        const int o = m;
        float v = 0.f;
        #pragma unroll
        for (int k=0;k<EMB;k++) v += sm.p.sWue[o*33+k] * sm.p.sA[li*33+k];
        eau_s[(size_t)pos*EMB + o] = v;
        if (o < HEADS){
          float u = 0.f;
          #pragma unroll
          for (int k=0;k<EMB;k++)
            u += sm.p.sWedge[o*64+k]*sm.p.sA[li*33+k] + sm.p.sWedge[o*64+EMB+k]*sm.p.sT[li*33+k];
          se_s[(size_t)pos*4 + o] = u;
        }
      }
      __syncthreads();
    }
  }
  grid.sync();

  // ---------------- P5: per-row softmax + output ----------------
  for (int r = b; r < NN; r += GRID){
    __syncthreads();
    const int lane = t & 63, wid = t >> 6;
    const int off0 = offs[r];
    const int deg = offs[r+1] - off0;

    if (deg <= 0){
      if (t < 96) out[(size_t)r*96 + t] = slnb[t & 31] * (1.0f/NN);
      continue;
    }

    const float t0 = tar[r*4+0], t1 = tar[r*4+1], t2 = tar[r*4+2];

    float m0=-1e30f, m1=-1e30f, m2=-1e30f;
    for (int base=0; base<deg; base+=256){
      const int k = base + t;
      if (k < deg){
        const int j = dsts[off0+k];
        const float* se = &se_s[(size_t)(off0+k)*4];
        const float* nj = &nbr[(size_t)j*4];
        const float s0 = lrelu(t0 + se[0] + nj[0]);
        const float s1 = lrelu(t1 + se[1] + nj[1]);
        const float s2 = lrelu(t2 + se[2] + nj[2]);
        if (base == 0){ sm.r.dst_c[t]=j; sm.r.s_c[0][t]=s0; sm.r.s_c[1][t]=s1; sm.r.s_c[2][t]=s2; }
        m0 = fmaxf(m0, s0); m1 = fmaxf(m1, s1); m2 = fmaxf(m2, s2);
      }
    }
    for (int d=32; d; d>>=1){
      m0 = fmaxf(m0, __shfl_xor(m0, d, 64));
      m1 = fmaxf(m1, __shfl_xor(m1, d, 64));
      m2 = fmaxf(m2, __shfl_xor(m2, d, 64));
    }
    if (lane == 0){ sm.r.red[0][wid]=m0; sm.r.red[1][wid]=m1; sm.r.red[2][wid]=m2; }
    __syncthreads();
    if (t == 0){
      sm.r.bcast[0] = fmaxf(fmaxf(sm.r.red[0][0],sm.r.red[0][1]), fmaxf(sm.r.red[0][2],sm.r.red[0][3]));
      sm.r.bcast[1] = fmaxf(fmaxf(sm.r.red[1][0],sm.r.red[1][1]), fmaxf(sm.r.red[1][2],sm.r.red[1][3]));
      sm.r.bcast[2] = fmaxf(fmaxf(sm.r.red[2][0],sm.r.red[2][1]), fmaxf(sm.r.red[2][2],sm.r.red[2][3]));
    }
    __syncthreads();
    const float M0=sm.r.bcast[0], M1=sm.r.bcast[1], M2=sm.r.bcast[2];

    float den0=0.f, den1=0.f, den2=0.f;
    float accv = 0.f;
    const int h = t >> 5, o = t & 31;   // valid for t<96
    for (int base=0; base<deg; base+=256){
      const int cdeg = min(256, deg-base);
      const int k = base + t;
      __syncthreads();
      if (k < deg){
        int j; float s0,s1,s2;
        if (base == 0){
          j = sm.r.dst_c[t]; s0 = sm.r.s_c[0][t]; s1 = sm.r.s_c[1][t]; s2 = sm.r.s_c[2][t];
        } else {
          j = dsts[off0+k];
          const float* se = &se_s[(size_t)(off0+k)*4];
          const float* nj = &nbr[(size_t)j*4];
          s0 = lrelu(t0+se[0]+nj[0]); s1 = lrelu(t1+se[1]+nj[1]); s2 = lrelu(t2+se[2]+nj[2]);
          sm.r.dst_c[t] = j;
        }
        const float p0 = __expf(s0 - M0);
        const float p1 = __expf(s1 - M1);
        const float p2 = __expf(s2 - M2);
        sm.r.p_c[0][t]=p0; sm.r.p_c[1][t]=p1; sm.r.p_c[2][t]=p2;
        den0+=p0; den1+=p1; den2+=p2;
      }
      __syncthreads();
      for (int idx=t; idx<cdeg*EMB; idx+=256){
        const int kk = idx >> 5, oo = idx & 31;
        sm.r.u_c[idx] = lrelu(eau_s[(size_t)(off0+base+kk)*EMB + oo]
                              + nb[(size_t)sm.r.dst_c[kk]*EMB + oo]);
      }
      __syncthreads();
      if (t < 96){
        float a = 0.f;
        for (int kk=0; kk<cdeg; kk++) a += sm.r.p_c[h][kk] * sm.r.u_c[kk*EMB + o];
        accv += a;
      }
    }
    for (int d=32; d; d>>=1){
      den0 += __shfl_xor(den0, d, 64);
      den1 += __shfl_xor(den1, d, 64);
      den2 += __shfl_xor(den2, d, 64);
    }
    __syncthreads();
    if (lane == 0){ sm.r.red[0][wid]=den0; sm.r.red[1][wid]=den1; sm.r.red[2][wid]=den2; }
    __syncthreads();
    if (t == 0){
      sm.r.bcast[0] = sm.r.red[0][0]+sm.r.red[0][1]+sm.r.red[0][2]+sm.r.red[0][3];
      sm.r.bcast[1] = sm.r.red[1][0]+sm.r.red[1][1]+sm.r.red[1][2]+sm.r.red[1][3];
      sm.r.bcast[2] = sm.r.red[2][0]+sm.r.red[2][1]+sm.r.red[2][2]+sm.r.red[2][3];
    }
    __syncthreads();
    if (t < 96) out[(size_t)r*96 + t] = accv / sm.r.bcast[h];
  }
}

// =================== fallback multi-kernel path (proven, round 5) ===================
__global__ __launch_bounds__(256) void k_node(
    const float* __restrict__ node_f, const float* __restrict__ W_veh,
    const float* __restrict__ W_ped, const float* __restrict__ W_att,
    const float* __restrict__ W_upd, const unsigned char* __restrict__ veh_mask,
    float* __restrict__ tar, float* __restrict__ nbr,
    float* __restrict__ nb, float* __restrict__ slnb)
{
  __shared__ float sWvehT[EMB*33], sWpedT[EMB*33], sWunT[EMB*33];
  __shared__ float sWt[HEADS*EMB], sWn[HEADS*EMB];
  __shared__ float sF[8*EMB], sEmb[8*EMB], sLr[EMB];
  __shared__ int layout_s;
  const int t = threadIdx.x;
  const int i0 = blockIdx.x*8;
  if (t == 0) layout_s = detect_mask_layout(veh_mask);
  if (t < EMB) sLr[t] = 0.f;
  for (int idx=t; idx<EMB*EMB; idx+=256){
    const int mm = idx>>5, kk = idx&31;
    sWvehT[mm*33+kk] = W_veh[idx];
    sWpedT[mm*33+kk] = W_ped[idx];
    sWunT[mm*33+kk]  = W_upd[mm*64 + EMB + kk];
  }
  if (t < HEADS*EMB){
    const int h = t>>5, c = t&31;
    sWt[t] = W_att[h*128 + c];
    sWn[t] = W_att[h*128 + 96 + c];
  }
  sF[t] = node_f[(size_t)i0*EMB + t];
  __syncthreads();
  const int li = t >> 5, m = t & 31;
  const int i = i0 + li;
  const bool veh = mask_at(veh_mask, layout_s, i);
  const float* WT = veh ? sWvehT : sWpedT;
  float a = 0.f;
  #pragma unroll
  for (int k=0;k<EMB;k++) a += sF[li*EMB+k] * WT[m*33+k];
  sEmb[li*EMB+m] = lrelu(a);
  __syncthreads();
  float b = 0.f;
  #pragma unroll
  for (int k=0;k<EMB;k++) b += sEmb[li*EMB+k] * sWunT[m*33+k];
  nb[(size_t)i*EMB + m] = b;
  atomicAdd(&sLr[m], lrelu(b));
  if (m < 3){
    float v = 0.f;
    #pragma unroll
    for (int k=0;k<EMB;k++) v += sEmb[li*EMB+k] * sWt[m*EMB+k];
    tar[i*4+m] = v;
  } else if (m < 6){
    const int h = m-3;
    float v = 0.f;
    #pragma unroll
    for (int k=0;k<EMB;k++) v += sEmb[li*EMB+k] * sWn[h*EMB+k];
    nbr[i*4+h] = v;
  }
  __syncthreads();
  if (t < EMB) atomicAdd(&slnb[t], sLr[t]);
}

__global__ __launch_bounds__(256) void k_claim(const int* __restrict__ ei,
                                               int* __restrict__ M, int* __restrict__ nxt,
                                               int* __restrict__ cnt)
{
  const int e = blockIdx.x*256 + threadIdx.x;
  const int s = ei[e], d = ei[EE + e];
  const int old = atomicExch(&M[s*NN + d], e);
  nxt[e] = old;
  if (old == -1) atomicAdd(&cnt[s], 1);
}

__global__ __launch_bounds__(256) void k_scan(const int* __restrict__ cnt, int* __restrict__ offs)
{
  __shared__ int warp_sums[4];
  const int t = threadIdx.x;
  const int lane = t & 63, wid = t >> 6;
  const int base = t*6;
  int v[6]; int s = 0;
  for (int k=0;k<6;k++){ v[k] = cnt[base+k]; s += v[k]; }
  int x = s;
  for (int d=1; d<64; d<<=1){ int y = __shfl_up(x, d, 64); if (lane >= d) x += y; }
  if (lane==63) warp_sums[wid] = x;
  __syncthreads();
  if (t==0){ int a=0; for (int w=0;w<4;w++){ int tmp=warp_sums[w]; warp_sums[w]=a; a+=tmp; } }
  __syncthreads();
  int run = (x - s) + warp_sums[wid];
  for (int k=0;k<6;k++){ offs[base+k] = run; run += v[k]; }
  if (t==255) offs[NN] = run;
}

__global__ __launch_bounds__(256) void k_slot(const int* __restrict__ ei,
                                              const int* __restrict__ M,
                                              const int* __restrict__ offs, int* __restrict__ fill,
                                              int* __restrict__ heads, int* __restrict__ dsts)
{
  const int e = blockIdx.x*256 + threadIdx.x;
  const int s = ei[e], d = ei[EE + e];
  if (M[s*NN + d] == e){
    const int pos = offs[s] + atomicAdd(&fill[s], 1);
    heads[pos] = e;
    dsts[pos] = d;
  }
}

__global__ __launch_bounds__(256) void k_pairs(
    const int* __restrict__ heads, const int* __restrict__ nxt,
    const float* __restrict__ edge_attr, const float* __restrict__ edge_type,
    const float* __restrict__ W_ea, const float* __restrict__ W_et,
    const float* __restrict__ W_att, const float* __restrict__ W_upd,
    const int* __restrict__ offs,
    float* __restrict__ se_s, float* __restrict__ eau_s)
{
  __shared__ float sWea[EMB*2], sWet[EMB*2], sWedge[HEADS*64], sWue[EMB*33];
  __shared__ float sA[8*33], sT[8*33];
  __shared__ int sNp;
  const int t = threadIdx.x;
  if (t == 0) sNp = offs[NN];
  if (t < EMB*2){ sWea[t]=W_ea[t]; sWet[t]=W_et[t]; }
  if (t < HEADS*64) sWedge[t] = W_att[(t>>6)*128 + EMB + (t&63)];
  for (int idx=t; idx<EMB*EMB; idx+=256){
    const int o = idx>>5, m = idx&31;
    sWue[o*33+m] = W_upd[o*64 + m];
  }
  __syncthreads();
  const int li = t >> 5, m = t & 31;
  const int pos = blockIdx.x*8 + li;
  const bool live = (pos < sNp);
  if (live){
    float am = 0.f, tm = 0.f;
    const float wa0 = sWea[m*2], wa1 = sWea[m*2+1];
    const float wt0 = sWet[m*2], wt1 = sWet[m*2+1];
    int e = heads[pos];
    while (e >= 0){
      const float ea0 = edge_attr[e*2],  ea1 = edge_attr[e*2+1];
      const float et0 = edge_type[e*2],  et1 = edge_type[e*2+1];
      am += lrelu(ea0*wa0 + ea1*wa1);
      tm += lrelu(et0*wt0 + et1*wt1);
      e = nxt[e];
    }
    sA[li*33+m] = am;
    sT[li*33+m] = tm;
  }
  __syncthreads();
  if (live){
    const int o = m;
    float v = 0.f;
    #pragma unroll
    for (int k=0;k<EMB;k++) v += sWue[o*33+k] * sA[li*33+k];
    eau_s[(size_t)pos*EMB + o] = v;
    if (o < HEADS){
      float u = 0.f;
      #pragma unroll
      for (int k=0;k<EMB;k++) u += sWedge[o*64+k]*sA[li*33+k] + sWedge[o*64+EMB+k]*sT[li*33+k];
      se_s[(size_t)pos*4 + o] = u;
    }
  }
}

__global__ __launch_bounds__(256) void k_rows(
    const int* __restrict__ offs, const int* __restrict__ dsts,
    const float* __restrict__ se_s, const float* __restrict__ eau_s,
    const float* __restrict__ tar, const float* __restrict__ nbr,
    const float* __restrict__ nb, const float* __restrict__ slnb,
    float* __restrict__ out)
{
  const int r = blockIdx.x;
  const int t = threadIdx.x;
  const int lane = t & 63, wid = t >> 6;
  const int off0 = offs[r];
  const int deg = offs[r+1] - off0;
  __shared__ int   dst_c[256];
  __shared__ float s_c[3][256];
  __shared__ float p_c[3][256];
  __shared__ float u_c[256*EMB];
  __shared__ float red[3][4];
  __shared__ float bcast[3];
  if (deg <= 0){
    if (t < 96) out[(size_t)r*96 + t] = slnb[t & 31] * (1.0f/NN);
    return;
  }
  const float t0 = tar[r*4+0], t1 = tar[r*4+1], t2 = tar[r*4+2];
  float m0=-1e30f, m1=-1e30f, m2=-1e30f;
  for (int base=0; base<deg; base+=256){
    const int k = base + t;
    if (k < deg){
      const int j = dsts[off0+k];
      const float* se = &se_s[(size_t)(off0+k)*4];
      const float* nj = &nbr[(size_t)j*4];
      const float s0 = lrelu(t0 + se[0] + nj[0]);
      const float s1 = lrelu(t1 + se[1] + nj[1]);
      const float s2 = lrelu(t2 + se[2] + nj[2]);
      if (base == 0){ dst_c[t]=j; s_c[0][t]=s0; s_c[1][t]=s1; s_c[2][t]=s2; }
      m0 = fmaxf(m0, s0); m1 = fmaxf(m1, s1); m2 = fmaxf(m2, s2);
    }
  }
  for (int d=32; d; d>>=1){
    m0 = fmaxf(m0, __shfl_xor(m0, d, 64));
    m1 = fmaxf(m1, __shfl_xor(m1, d, 64));
    m2 = fmaxf(m2, __shfl_xor(m2, d, 64));
  }
  if (lane == 0){ red[0][wid]=m0; red[1][wid]=m1; red[2][wid]=m2; }
  __syncthreads();
  if (t == 0){
    bcast[0] = fmaxf(fmaxf(red[0][0],red[0][1]), fmaxf(red[0][2],red[0][3]));
    bcast[1] = fmaxf(fmaxf(red[1][0],red[1][1]), fmaxf(red[1][2],red[1][3]));
    bcast[2] = fmaxf(fmaxf(red[2][0],red[2][1]), fmaxf(red[2][2],red[2][3]));
  }
  __syncthreads();
  const float M0=bcast[0], M1=bcast[1], M2=bcast[2];
  float den0=0.f, den1=0.f, den2=0.f;
  float accv = 0.f;
  const int h = t >> 5, o = t & 31;
  for (int base=0; base<deg; base+=256){
    const int cdeg = min(256, deg-base);
    const int k = base + t;
    __syncthreads();
    if (k < deg){
      int j; float s0,s1,s2;
      if (base == 0){
        j = dst_c[t]; s0 = s_c[0][t]; s1 = s_c[1][t]; s2 = s_c[2][t];
      } else {
        j = dsts[off0+k];
        const float* se = &se_s[(size_t)(off0+k)*4];
        const float* nj = &nbr[(size_t)j*4];
        s0 = lrelu(t0+se[0]+nj[0]); s1 = lrelu(t1+se[1]+nj[1]); s2 = lrelu(t2+se[2]+nj[2]);
        dst_c[t] = j;
      }
      const float p0 = __expf(s0 - M0);
      const float p1 = __expf(s1 - M1);
      const float p2 = __expf(s2 - M2);
      p_c[0][t]=p0; p_c[1][t]=p1; p_c[2][t]=p2;
      den0+=p0; den1+=p1; den2+=p2;
    }
    __syncthreads();
    for (int idx=t; idx<cdeg*EMB; idx+=256){
      const int kk = idx >> 5, oo = idx & 31;
      u_c[idx] = lrelu(eau_s[(size_t)(off0+base+kk)*EMB + oo] + nb[(size_t)dst_c[kk]*EMB + oo]);
    }
    __syncthreads();
    if (t < 96){
      float a = 0.f;
      for (int kk=0; kk<cdeg; kk++) a += p_c[h][kk] * u_c[kk*EMB + o];
      accv += a;
    }
  }
  for (int d=32; d; d>>=1){
    den0 += __shfl_xor(den0, d, 64);
    den1 += __shfl_xor(den1, d, 64);
    den2 += __shfl_xor(den2, d, 64);
  }
  __syncthreads();
  if (lane == 0){ red[0][wid]=den0; red[1][wid]=den1; red[2][wid]=den2; }
  __syncthreads();
  if (t == 0){
    bcast[0] = red[0][0]+red[0][1]+red[0][2]+red[0][3];
    bcast[1] = red[1][0]+red[1][1]+red[1][2]+red[1][3];
    bcast[2] = red[2][0]+red[2][1]+red[2][2]+red[2][3];
  }
  __syncthreads();
  if (t < 96) out[(size_t)r*96 + t] = accv / bcast[h];
}

extern "C" void kernel_launch(void* const* d_in, const int* in_sizes, int n_in,
                              void* d_out, int out_size, void* d_ws, size_t ws_size,
                              hipStream_t stream)
{
  (void)in_sizes; (void)n_in; (void)out_size; (void)ws_size;
  const float* node_f    = (const float*)d_in[0];
  const float* edge_attr = (const float*)d_in[1];
  const float* edge_type = (const float*)d_in[2];
  const float* W_veh     = (const float*)d_in[3];
  const float* W_ped     = (const float*)d_in[4];
  const float* W_ea      = (const float*)d_in[5];
  const float* W_et      = (const float*)d_in[6];
  const float* W_att     = (const float*)d_in[7];
  const float* W_upd     = (const float*)d_in[8];
  const int*   ei        = (const int*)d_in[9];
  const unsigned char* veh_mask = (const unsigned char*)d_in[10];
  float* out = (float*)d_out;

  char* ws = (char*)d_ws;
  const size_t oM    = 0;
  const size_t oCnt  = oM    + (size_t)NN*NN*4;
  const size_t oFill = oCnt  + (size_t)NN*4;
  const size_t oSlnb = oFill + (size_t)NN*4;
  const size_t zend  = oSlnb + (size_t)EMB*4;
  const size_t oOff  = zend;
  const size_t oNxt  = oOff  + 6160;
  const size_t oHead = oNxt  + (size_t)EE*4;
  const size_t oDst  = oHead + (size_t)EE*4;
  const size_t oSe   = oDst  + (size_t)EE*4;
  const size_t oEau  = oSe   + (size_t)EE*4*4;
  const size_t oTar  = oEau  + (size_t)EE*EMB*4;
  const size_t oNbr  = oTar  + (size_t)NN*4*4;
  const size_t oNb   = oNbr  + (size_t)NN*4*4;

  int*   M     = (int*)  (ws + oM);
  int*   cnt   = (int*)  (ws + oCnt);
  int*   fill  = (int*)  (ws + oFill);
  float* slnb  = (float*)(ws + oSlnb);
  int*   offs  = (int*)  (ws + oOff);
  int*   nxt   = (int*)  (ws + oNxt);
  int*   heads = (int*)  (ws + oHead);
  int*   dsts  = (int*)  (ws + oDst);
  float* se_s  = (float*)(ws + oSe);
  float* eau_s = (float*)(ws + oEau);
  float* tar   = (float*)(ws + oTar);
  float* nbr   = (float*)(ws + oNbr);
  float* nb    = (float*)(ws + oNb);

  void* args[] = {
    &node_f, &edge_attr, &edge_type, &W_veh, &W_ped, &W_ea, &W_et, &W_att, &W_upd,
    &ei, &veh_mask, &out,
    &M, &cnt, &fill, &slnb, &offs, &nxt, &heads, &dsts, &se_s, &eau_s, &tar, &nbr, &nb
  };
  hipError_t err = hipLaunchCooperativeKernel((const void*)k_fused, dim3(GRID), dim3(256),
                                              args, 0, stream);
  if (err != hipSuccess){
    // fallback: proven 8-dispatch path
    hipMemsetAsync(ws + oM,   0xFF, (size_t)NN*NN*4, stream);
    hipMemsetAsync(ws + oCnt, 0,    zend - oCnt,     stream);
    k_node <<<NN/8,    256, 0, stream>>>(node_f, W_veh, W_ped, W_att, W_upd, veh_mask,
                                         tar, nbr, nb, slnb);
    k_claim<<<EE/256,  256, 0, stream>>>(ei, M, nxt, cnt);
    k_scan <<<1,       256, 0, stream>>>(cnt, offs);
    k_slot <<<EE/256,  256, 0, stream>>>(ei, M, offs, fill, heads, dsts);
    k_pairs<<<EE/8,    256, 0, stream>>>(heads, nxt, edge_attr, edge_type,
                                         W_ea, W_et, W_att, W_upd, offs, se_s, eau_s);
    k_rows <<<NN,      256, 0, stream>>>(offs, dsts, se_s, eau_s, tar, nbr, nb, slnb, out);
  }
}

// Round 7
// 127.652 us; speedup vs baseline: 3.4285x; 3.4285x over previous
//
#include <hip/hip_runtime.h>
#include <stdint.h>

#define NN 1536
#define EE 49152
#define EMB 32
#define HEADS 3
#define SLOPE 0.2f
#define MAXP 1536          // worst-case distinct dsts per row (fully safe)
#define CHUNK 64

__device__ __forceinline__ float lrelu(float x){ return x >= 0.f ? x : SLOPE*x; }

// ---- runtime detection of bool-mask storage (int32 / uint8 / f32) ----
__device__ int detect_mask_layout(const unsigned char* p){
  const int* pi = (const int*)p;
  bool ok = true;
  for (int k=0;k<64 && ok;k++){ int v = pi[k]; ok = (v==0 || v==1); }
  if (ok) return 0;                       // int32 0/1
  ok = true;
  for (int k=0;k<256 && ok;k++){ ok = (p[k] <= 1); }
  if (ok) return 1;                       // uint8 bool
  return 2;                               // f32 0.0/1.0
}
__device__ bool mask_at(const unsigned char* p, int layout, int i){
  if (layout==0) return ((const int*)p)[i] != 0;
  if (layout==1) return p[i] != 0;
  return ((const float*)p)[i] != 0.f;
}

// ---- K1: blocks [0,192): edge claim (linked list). blocks [192,384): node emb ----
__global__ __launch_bounds__(256) void k_prep(
    const float* __restrict__ node_f,
    const float* __restrict__ W_veh, const float* __restrict__ W_ped,
    const float* __restrict__ W_att, const float* __restrict__ W_upd,
    const int* __restrict__ ei, const unsigned char* __restrict__ veh_mask,
    int* __restrict__ M, int* __restrict__ nxt,
    float* __restrict__ tar, float* __restrict__ nbr, float* __restrict__ nb)
{
  const int t = threadIdx.x;
  const int b = blockIdx.x;

  if (b < EE/256){
    // -------- claim path: per-pair linked list via atomicExch --------
    const int e = b*256 + t;
    const int s = ei[e], d = ei[EE + e];
    nxt[e] = atomicExch(&M[s*NN + d], e);
    return;
  }

  // -------- node path: 8 nodes/block, 32 threads/node --------
  __shared__ float sWvehT[EMB*33], sWpedT[EMB*33], sWunT[EMB*33];
  __shared__ float sWt[HEADS*EMB], sWn[HEADS*EMB];
  __shared__ float sF[8*EMB], sEmb[8*EMB];
  __shared__ int layout_s;
  const int i0 = (b - EE/256)*8;
  if (t == 0) layout_s = detect_mask_layout(veh_mask);
  for (int idx=t; idx<EMB*EMB; idx+=256){
    const int mm = idx>>5, kk = idx&31;
    sWvehT[mm*33+kk] = W_veh[idx];
    sWpedT[mm*33+kk] = W_ped[idx];
    sWunT[mm*33+kk]  = W_upd[mm*64 + EMB + kk];   // Wu_n = W_upd[:,32:]
  }
  if (t < HEADS*EMB){
    const int h = t>>5, c = t&31;
    sWt[t] = W_att[h*128 + c];        // W_tar = W_att[:, :32]
    sWn[t] = W_att[h*128 + 96 + c];   // W_nbr = W_att[:, 96:128]
  }
  sF[t] = node_f[(size_t)i0*EMB + t];
  __syncthreads();

  const int li = t >> 5, m = t & 31;
  const int i = i0 + li;
  const bool veh = mask_at(veh_mask, layout_s, i);
  const float* WT = veh ? sWvehT : sWpedT;
  float a = 0.f;
  #pragma unroll
  for (int k=0;k<EMB;k++) a += sF[li*EMB+k] * WT[m*33+k];
  sEmb[li*EMB+m] = lrelu(a);
  __syncthreads();

  float bb = 0.f;
  #pragma unroll
  for (int k=0;k<EMB;k++) bb += sEmb[li*EMB+k] * sWunT[m*33+k];
  nb[(size_t)i*EMB + m] = bb;
  if (m < 3){
    float v = 0.f;
    #pragma unroll
    for (int k=0;k<EMB;k++) v += sEmb[li*EMB+k] * sWt[m*EMB+k];
    tar[i*4+m] = v;
  } else if (m < 6){
    const int h = m-3;
    float v = 0.f;
    #pragma unroll
    for (int k=0;k<EMB;k++) v += sEmb[li*EMB+k] * sWn[h*EMB+k];
    nbr[i*4+h] = v;
  }
}

// ---- K2: one block per src row. Scan M row -> pairs; chain-walk + embed +
//          online softmax + output, all in-block (no se/eau global round-trip).
__global__ __launch_bounds__(256) void k_rows(
    const int* __restrict__ M, const int* __restrict__ nxt,
    const float* __restrict__ edge_attr, const float* __restrict__ edge_type,
    const float* __restrict__ W_ea, const float* __restrict__ W_et,
    const float* __restrict__ W_att, const float* __restrict__ W_upd,
    const float* __restrict__ tar, const float* __restrict__ nbr,
    const float* __restrict__ nb, float* __restrict__ out)
{
  const int r = blockIdx.x;
  const int t = threadIdx.x;

  __shared__ int   pd[MAXP], pe[MAXP];
  __shared__ int   npair;
  __shared__ float sWea[EMB*2], sWet[EMB*2], sWedge[HEADS*64], sWueT[EMB*33];
  __shared__ float sA[CHUNK*33], sT[CHUNK*33];
  __shared__ float u_c[CHUNK*EMB];
  __shared__ float sc[192], p_c[192];
  __shared__ float m_run[3], l_run[3], alpha_s[3];

  if (t == 0) npair = 0;
  if (t < 3){ m_run[t] = -1e30f; l_run[t] = 0.f; }
  if (t < EMB*2){ sWea[t] = W_ea[t]; sWet[t] = W_et[t]; }
  if (t < HEADS*64) sWedge[t] = W_att[(t>>6)*128 + EMB + (t&63)];  // W_edge
  for (int idx=t; idx<EMB*EMB; idx+=256){
    const int o = idx>>5, k = idx&31;
    sWueT[o*33+k] = W_upd[o*64 + k];          // Wu_e = W_upd[:, :32]
  }
  __syncthreads();

  // R1: scan this row of M, compact live (dst, winner-edge) pairs
  for (int j=t; j<NN; j+=256){
    const int v = M[(size_t)r*NN + j];
    if (v >= 0){
      const int idx = atomicAdd(&npair, 1);
      pd[idx] = j; pe[idx] = v;
    }
  }
  __syncthreads();
  const int Np = npair;

  if (Np == 0){
    // all scores -10000 -> uniform attention over all n nodes (lazy fallback)
    __shared__ float fb[EMB];
    if (t < EMB) fb[t] = 0.f;
    __syncthreads();
    for (int idx=t; idx<NN*EMB; idx+=256)
      atomicAdd(&fb[idx&31], lrelu(nb[idx]));
    __syncthreads();
    if (t < 96) out[(size_t)r*96 + t] = fb[t&31] * (1.0f/NN);
    return;
  }

  float acc = 0.f;
  const int li = t >> 5, m = t & 31;
  const float wa0 = sWea[m*2], wa1 = sWea[m*2+1];
  const float wt0 = sWet[m*2], wt1 = sWet[m*2+1];

  for (int c0 = 0; c0 < Np; c0 += CHUNK){
    const int Cc = min(CHUNK, Np - c0);

    // A: pair-group li handles pairs q = li, li+8, ...; lane m -> element m
    for (int q = li; q < Cc; q += 8){
      float am = 0.f, tm = 0.f;
      int e = pe[c0+q];
      while (e >= 0){                          // dup chain, length 1 for ~99.4%
        const float2 ea = ((const float2*)edge_attr)[e];
        const float2 et = ((const float2*)edge_type)[e];
        am += lrelu(ea.x*wa0 + ea.y*wa1);
        tm += lrelu(et.x*wt0 + et.y*wt1);
        e = nxt[e];
      }
      sA[q*33+m] = am;
      sT[q*33+m] = tm;
    }
    __syncthreads();

    // C: scores (t<192: h = t>>6, q = t&63)   D: u values (all 256 threads)
    if (t < 192){
      const int h = t>>6, q = t&63;
      if (q < Cc){
        float se = 0.f;
        #pragma unroll
        for (int k=0;k<EMB;k++)
          se += sWedge[h*64+k]*sA[q*33+k] + sWedge[h*64+EMB+k]*sT[q*33+k];
        sc[t] = lrelu(tar[r*4+h] + se + nbr[pd[c0+q]*4+h]);
      }
    }
    for (int idx=t; idx<Cc*EMB; idx+=256){
      const int q = idx>>5, o = idx&31;
      float v = 0.f;
      #pragma unroll
      for (int k=0;k<EMB;k++) v += sWueT[o*33+k]*sA[q*33+k];
      u_c[idx] = lrelu(v + nb[(size_t)pd[c0+q]*EMB + o]);
    }
    __syncthreads();

    // F1: per-head chunk max + rescale factor (online softmax)
    if (t < 3){
      float mn = m_run[t];
      for (int q=0;q<Cc;q++) mn = fmaxf(mn, sc[t*64+q]);
      alpha_s[t] = __expf(m_run[t] - mn);
      m_run[t] = mn;
    }
    __syncthreads();

    // F3: p = exp(s - m), per-head denominator update (head h == wave h)
    if (t < 192){
      const int h = t>>6, q = t&63;
      float p = (q < Cc) ? __expf(sc[t] - m_run[h]) : 0.f;
      p_c[t] = p;
      float sum = p;
      for (int d=32; d; d>>=1) sum += __shfl_xor(sum, d, 64);
      if ((t&63) == 0) l_run[h] = l_run[h]*alpha_s[h] + sum;
    }
    __syncthreads();

    // G: accumulator update
    if (t < 96){
      const int h = t>>5, o = t&31;
      float a2 = 0.f;
      for (int q=0;q<Cc;q++) a2 += p_c[h*64+q]*u_c[q*32+o];
      acc = acc*alpha_s[h] + a2;
    }
    // next chunk's post-A __syncthreads guards LDS reuse
  }

  if (t < 96) out[(size_t)r*96 + t] = acc / l_run[t>>5];
}

extern "C" void kernel_launch(void* const* d_in, const int* in_sizes, int n_in,
                              void* d_out, int out_size, void* d_ws, size_t ws_size,
                              hipStream_t stream)
{
  (void)in_sizes; (void)n_in; (void)out_size; (void)ws_size;
  const float* node_f    = (const float*)d_in[0];
  const float* edge_attr = (const float*)d_in[1];
  const float* edge_type = (const float*)d_in[2];
  const float* W_veh     = (const float*)d_in[3];
  const float* W_ped     = (const float*)d_in[4];
  const float* W_ea      = (const float*)d_in[5];
  const float* W_et      = (const float*)d_in[6];
  const float* W_att     = (const float*)d_in[7];
  const float* W_upd     = (const float*)d_in[8];
  const int*   ei        = (const int*)d_in[9];
  const unsigned char* veh_mask = (const unsigned char*)d_in[10];
  float* out = (float*)d_out;

  char* ws = (char*)d_ws;
  const size_t oM   = 0;                          // N*N ints (pair map)
  const size_t oNxt = oM   + (size_t)NN*NN*4;     // E ints
  const size_t oTar = oNxt + (size_t)EE*4;        // N*4 floats
  const size_t oNbr = oTar + (size_t)NN*4*4;      // N*4 floats
  const size_t oNb  = oNbr + (size_t)NN*4*4;      // N*32 floats

  int*   M    = (int*)  (ws + oM);
  int*   nxt  = (int*)  (ws + oNxt);
  float* tar  = (float*)(ws + oTar);
  float* nbr  = (float*)(ws + oNbr);
  float* nb   = (float*)(ws + oNb);

  hipMemsetAsync(ws + oM, 0xFF, (size_t)NN*NN*4, stream);   // M = -1

  k_prep<<<EE/256 + NN/8, 256, 0, stream>>>(node_f, W_veh, W_ped, W_att, W_upd,
                                            ei, veh_mask, M, nxt, tar, nbr, nb);
  k_rows<<<NN, 256, 0, stream>>>(M, nxt, edge_attr, edge_type,
                                 W_ea, W_et, W_att, W_upd, tar, nbr, nb, out);
}